// Round 1
// baseline (176.672 us; speedup 1.0000x reference)
//
#include <hip/hip_runtime.h>

// Point-splat renderer:
//   winner[pix] = max point index projecting to pix (atomicMax, deterministic)
//   out[c][pix] = clip(colors[winner[pix]][c], 0, 1) or 0
//
// Inputs (setup_inputs order):
//   d_in[0] positions (N*3 f32)
//   d_in[1] colors    (N*3 f32)
//   d_in[2] camera_pose (16 f32, row-major 4x4)
//   d_in[3] intrinsics  (9 f32, row-major 3x3)
//   d_in[4] H (1 int)
//   d_in[5] W (1 int)
// Output: (1,3,H,W) f32 flat.

__global__ void proj_kernel(const float* __restrict__ pos,
                            const float* __restrict__ pose,
                            const float* __restrict__ intr,
                            const int* __restrict__ Hp,
                            const int* __restrict__ Wp,
                            int* __restrict__ winner,
                            int n) {
    int i = blockIdx.x * blockDim.x + threadIdx.x;
    if (i >= n) return;

    float px = pos[3 * i + 0];
    float py = pos[3 * i + 1];
    float pz = pos[3 * i + 2];

    // pc = R * p + t   (reference: positions @ R.T + t)
    float x = pose[0] * px + pose[1] * py + pose[2]  * pz + pose[3];
    float y = pose[4] * px + pose[5] * py + pose[6]  * pz + pose[7];
    float z = pose[8] * px + pose[9] * py + pose[10] * pz + pose[11];

    float fx = intr[0], cx = intr[2];
    float fy = intr[4], cy = intr[5];

    float u = fx * x / z + cx;
    float v = fy * y / z + cy;

    int xi = (int)u;   // truncation toward zero == numpy astype(int32)
    int yi = (int)v;

    int W = *Wp, H = *Hp;
    if (xi >= 0 && xi < W && yi >= 0 && yi < H) {
        atomicMax(&winner[yi * W + xi], i);
    }
}

__global__ void paint_kernel(const int* __restrict__ winner,
                             const float* __restrict__ colors,
                             float* __restrict__ out,
                             int HW) {
    int p = blockIdx.x * blockDim.x + threadIdx.x;
    if (p >= HW) return;

    int w = winner[p];
    float r = 0.0f, g = 0.0f, b = 0.0f;
    if (w >= 0) {
        r = colors[3 * w + 0];
        g = colors[3 * w + 1];
        b = colors[3 * w + 2];
        r = fminf(fmaxf(r, 0.0f), 1.0f);
        g = fminf(fmaxf(g, 0.0f), 1.0f);
        b = fminf(fmaxf(b, 0.0f), 1.0f);
    }
    out[p] = r;
    out[HW + p] = g;
    out[2 * HW + p] = b;
}

extern "C" void kernel_launch(void* const* d_in, const int* in_sizes, int n_in,
                              void* d_out, int out_size, void* d_ws, size_t ws_size,
                              hipStream_t stream) {
    const float* positions = (const float*)d_in[0];
    const float* colors    = (const float*)d_in[1];
    const float* pose      = (const float*)d_in[2];
    const float* intr      = (const float*)d_in[3];
    const int*   Hp        = (const int*)d_in[4];
    const int*   Wp        = (const int*)d_in[5];
    float* out = (float*)d_out;

    int n  = in_sizes[0] / 3;       // number of points
    int HW = out_size / 3;          // H*W pixels

    int* winner = (int*)d_ws;       // HW int32s

    // winner = -1 everywhere (0xFF bytes)
    hipMemsetAsync(winner, 0xFF, (size_t)HW * sizeof(int), stream);

    int block = 256;
    int grid1 = (n + block - 1) / block;
    proj_kernel<<<grid1, block, 0, stream>>>(positions, pose, intr, Hp, Wp, winner, n);

    int grid2 = (HW + block - 1) / block;
    paint_kernel<<<grid2, block, 0, stream>>>(winner, colors, out, HW);
}